// Round 1
// baseline (187.322 us; speedup 1.0000x reference)
//
#include <hip/hip_runtime.h>

#define Bn 4
#define Nn 2048
#define NBn 10

// ws layout in float (4-byte) units
#define OFF_PRED 0
#define OFF_GT   (Bn*Nn*16)
#define OFF_SYM  (2*Bn*Nn*16)
#define OFF_PN2  (3*Bn*Nn*16)
#define OFF_GN2  (OFF_PN2 + Bn*Nn)
#define OFF_SN2  (OFF_GN2 + Bn*Nn)
#define OFF_BEST (OFF_SN2 + Bn*Nn)      // uint32 per (b,n)
#define OFF_PK1  (OFF_BEST + Bn*Nn)     // u64 per (b,n)  (even float offset -> 8B aligned)
#define OFF_PK2  (OFF_PK1 + 2*Bn*Nn)
#define OFF_ACC  (OFF_PK2 + 2*Bn*Nn)    // 32 floats of accumulators

// acc: [0..3]=S_dir  [4..7]=S_app  [8..11]=S_off  [12..15]=S_succ
//      [16]=S_bce  [17]=S_adds  [18..21]=S_g2p

__device__ inline float sp_(float x) {            // jax.nn.softplus, stable form
  return fmaxf(x, 0.0f) + log1pf(expf(-fabsf(x)));
}

__device__ inline float dot16_(const float4&a0,const float4&a1,const float4&a2,const float4&a3,
                               const float4&b0,const float4&b1,const float4&b2,const float4&b3){
  float s0 = fmaf(a0.w,b0.w, fmaf(a0.z,b0.z, fmaf(a0.y,b0.y, a0.x*b0.x)));
  float s1 = fmaf(a1.w,b1.w, fmaf(a1.z,b1.z, fmaf(a1.y,b1.y, a1.x*b1.x)));
  float s2 = fmaf(a2.w,b2.w, fmaf(a2.z,b2.z, fmaf(a2.y,b2.y, a2.x*b2.x)));
  float s3 = fmaf(a3.w,b3.w, fmaf(a3.z,b3.z, fmaf(a3.y,b3.y, a3.x*b3.x)));
  return (s0+s1)+(s2+s3);
}

__device__ inline float blockSum_(float v, float* red) {
  #pragma unroll
  for (int o = 32; o > 0; o >>= 1) v += __shfl_down(v, o, 64);
  __syncthreads();
  if ((threadIdx.x & 63) == 0) red[threadIdx.x >> 6] = v;
  __syncthreads();
  return red[0] + red[1] + red[2] + red[3];
}

__global__ __launch_bounds__(256) void k_init(float* __restrict__ ws) {
  int i = blockIdx.x * 256 + threadIdx.x;                 // grid = 32 blocks -> 8192
  ((unsigned*)ws)[OFF_BEST + i] = 0x7F800000u;            // +inf
  ((unsigned long long*)(ws + OFF_PK1))[i] = ~0ull;
  ((unsigned long long*)(ws + OFF_PK2))[i] = ~0ull;
  if (i < 32) ws[OFF_ACC + i] = 0.0f;
}

__global__ __launch_bounds__(256) void k_prep(
    const float* __restrict__ gdir, const float* __restrict__ adirp,
    const float* __restrict__ goff, const float* __restrict__ ppts,
    const float* __restrict__ bsh,
    const float* __restrict__ dlab, const float* __restrict__ olab,
    const float* __restrict__ succ, const float* __restrict__ alab,
    const float* __restrict__ binv, const float* __restrict__ binw,
    const float* __restrict__ cpts, const float* __restrict__ scpts,
    float* __restrict__ ws)
{
  __shared__ float red[4];
  const int b = blockIdx.y;
  const int n = blockIdx.x * 256 + threadIdx.x;
  const int idx = b * Nn + n;

  const float gd0=gdir[idx*3+0],  gd1=gdir[idx*3+1],  gd2=gdir[idx*3+2];
  const float ad0=adirp[idx*3+0], ad1=adirp[idx*3+1], ad2=adirp[idx*3+2];
  const float dl0=dlab[idx*3+0],  dl1=dlab[idx*3+1],  dl2=dlab[idx*3+2];
  const float al0=alab[idx*3+0],  al1=alab[idx*3+1],  al2=alab[idx*3+2];
  const float pt0=ppts[idx*3+0],  pt1=ppts[idx*3+1],  pt2=ppts[idx*3+2];
  const float sc = succ[idx];

  // argmax (first occurrence, matches jnp.argmax)
  float bv = goff[idx*NBn]; int ap = 0;
  #pragma unroll
  for (int k = 1; k < NBn; k++) { float v = goff[idx*NBn+k]; if (v > bv) { bv = v; ap = k; } }
  float bg = olab[idx*NBn]; int ag = 0;
  #pragma unroll
  for (int k = 1; k < NBn; k++) { float v = olab[idx*NBn+k]; if (v > bg) { bg = v; ag = k; } }
  const float tp = binv[ap] * 0.5f;
  const float tg = binv[ag] * 0.5f;

  // frames: cross = cross(approach, base); t = pt + 0.5*thickness*base
  const float cp0 = ad1*gd2 - ad2*gd1, cp1 = ad2*gd0 - ad0*gd2, cp2 = ad0*gd1 - ad1*gd0;
  const float cg0 = al1*dl2 - al2*dl1, cg1 = al2*dl0 - al0*dl2, cg2 = al0*dl1 - al1*dl0;
  const float tpx = pt0 + tp*gd0, tpy = pt1 + tp*gd1, tpz = pt2 + tp*gd2;
  const float tgx = pt0 + tg*dl0, tgy = pt1 + tg*dl1, tgz = pt2 + tg*dl2;

  float pcp[16], gcp[16], hcp[16];
  float pn2 = 0.f, gn2 = 0.f, sn2 = 0.f;
  #pragma unroll
  for (int p = 0; p < 5; p++) {
    const float cx = cpts[p*3], cy = cpts[p*3+1], cz = cpts[p*3+2];
    const float sx = scpts[p*3], sy = scpts[p*3+1], sz = scpts[p*3+2];
    float x, y, z;
    // pred:  base=gd, cross=cp, approach=ad, t=tp*
    x = gd0*cx + cp0*cy + ad0*cz + tpx;
    y = gd1*cx + cp1*cy + ad1*cz + tpy;
    z = gd2*cx + cp2*cy + ad2*cz + tpz;
    pcp[p*3+0]=x; pcp[p*3+1]=y; pcp[p*3+2]=z;
    pn2 = fmaf(x,x, fmaf(y,y, fmaf(z,z, pn2)));
    // gt:    base=dl, cross=cg, approach=al, t=tg*
    x = dl0*cx + cg0*cy + al0*cz + tgx;
    y = dl1*cx + cg1*cy + al1*cz + tgy;
    z = dl2*cx + cg2*cy + al2*cz + tgz;
    gcp[p*3+0]=x; gcp[p*3+1]=y; gcp[p*3+2]=z;
    gn2 = fmaf(x,x, fmaf(y,y, fmaf(z,z, gn2)));
    // sym gt (same frame, permuted control pts)
    x = dl0*sx + cg0*sy + al0*sz + tgx;
    y = dl1*sx + cg1*sy + al1*sz + tgy;
    z = dl2*sx + cg2*sy + al2*sz + tgz;
    hcp[p*3+0]=x; hcp[p*3+1]=y; hcp[p*3+2]=z;
    sn2 = fmaf(x,x, fmaf(y,y, fmaf(z,z, sn2)));
  }
  pcp[15]=0.f; gcp[15]=0.f; hcp[15]=0.f;

  float4* pd = (float4*)(ws + OFF_PRED) + (size_t)idx*4;
  pd[0]=make_float4(pcp[0],pcp[1],pcp[2],pcp[3]);
  pd[1]=make_float4(pcp[4],pcp[5],pcp[6],pcp[7]);
  pd[2]=make_float4(pcp[8],pcp[9],pcp[10],pcp[11]);
  pd[3]=make_float4(pcp[12],pcp[13],pcp[14],0.f);
  float4* gdst = (float4*)(ws + OFF_GT) + (size_t)idx*4;
  gdst[0]=make_float4(gcp[0],gcp[1],gcp[2],gcp[3]);
  gdst[1]=make_float4(gcp[4],gcp[5],gcp[6],gcp[7]);
  gdst[2]=make_float4(gcp[8],gcp[9],gcp[10],gcp[11]);
  gdst[3]=make_float4(gcp[12],gcp[13],gcp[14],0.f);
  float4* sdst = (float4*)(ws + OFF_SYM) + (size_t)idx*4;
  sdst[0]=make_float4(hcp[0],hcp[1],hcp[2],hcp[3]);
  sdst[1]=make_float4(hcp[4],hcp[5],hcp[6],hcp[7]);
  sdst[2]=make_float4(hcp[8],hcp[9],hcp[10],hcp[11]);
  sdst[3]=make_float4(hcp[12],hcp[13],hcp[14],0.f);
  ws[OFF_PN2+idx] = pn2; ws[OFF_GN2+idx] = gn2; ws[OFF_SN2+idx] = sn2;

  // ---- cheap per-point losses ----
  const float cosd = 1.f - (dl0*gd0 + dl1*gd1 + dl2*gd2);
  const float proj = gd0*al0 + gd1*al1 + gd2*al2;
  const float o0 = al0 - proj*gd0, o1 = al1 - proj*gd1, o2 = al2 - proj*gd2;
  const float on = sqrtf(o0*o0 + o1*o1 + o2*o2);
  const float inv = 1.f / fmaxf(on, 1e-12f);
  const float cosa = 1.f - inv*(o0*ad0 + o1*ad1 + o2*ad2);

  float offv = 0.f;
  #pragma unroll
  for (int k = 0; k < NBn; k++) {
    const float x = goff[idx*NBn+k], lab = olab[idx*NBn+k];
    const float bce = lab * sp_(-x) + (1.f - lab) * sp_(x);
    offv = fmaf(binw[k], bce, offv);
  }
  offv *= (1.0f / NBn);
  const float sb = bsh[idx];
  const float sbce = sc * sp_(-sb) + (1.f - sc) * sp_(sb);

  float* acc = ws + OFF_ACC;
  float t;
  t = blockSum_(cosd*sc, red); if (threadIdx.x == 0) atomicAdd(&acc[0 + b], t);
  t = blockSum_(cosa*sc, red); if (threadIdx.x == 0) atomicAdd(&acc[4 + b], t);
  t = blockSum_(offv*sc, red); if (threadIdx.x == 0) atomicAdd(&acc[8 + b], t);
  t = blockSum_(sc, red);      if (threadIdx.x == 0) atomicAdd(&acc[12 + b], t);
  t = blockSum_(sbce, red);    if (threadIdx.x == 0) atomicAdd(&acc[16], t);
}

// forward: best[n] = min over succ-positive m of min(D1,D2). grid (mt, nt, b)
__global__ __launch_bounds__(256) void k_fwd(const float* __restrict__ succ,
                                             float* __restrict__ ws) {
  __shared__ float4 gts[256][4];
  __shared__ float4 sys[256][4];
  __shared__ float gb2s[256], sb2s[256], msk[256];
  const int b = blockIdx.z, nt = blockIdx.y, mt = blockIdx.x;
  const int tid = threadIdx.x;
  const int mrow = b*Nn + mt*256 + tid;
  const float4* gsrc = (const float4*)(ws + OFF_GT)  + (size_t)mrow*4;
  const float4* ssrc = (const float4*)(ws + OFF_SYM) + (size_t)mrow*4;
  gts[tid][0]=gsrc[0]; gts[tid][1]=gsrc[1]; gts[tid][2]=gsrc[2]; gts[tid][3]=gsrc[3];
  sys[tid][0]=ssrc[0]; sys[tid][1]=ssrc[1]; sys[tid][2]=ssrc[2]; sys[tid][3]=ssrc[3];
  gb2s[tid] = ws[OFF_GN2 + mrow];
  sb2s[tid] = ws[OFF_SN2 + mrow];
  msk[tid]  = succ[mrow];
  __syncthreads();

  const int nrow = b*Nn + nt*256 + tid;
  const float4* pa = (const float4*)(ws + OFF_PRED) + (size_t)nrow*4;
  const float4 a0 = pa[0], a1 = pa[1], a2 = pa[2], a3 = pa[3];
  const float an2 = ws[OFF_PN2 + nrow];

  float best = __int_as_float(0x7F800000);  // +inf
  for (int m = 0; m < 256; m++) {
    if (msk[m] != 0.0f) {
      const float dg = dot16_(a0,a1,a2,a3, gts[m][0],gts[m][1],gts[m][2],gts[m][3]);
      const float d1 = fmaxf(fmaf(-2.f, dg, an2 + gb2s[m]), 0.f);
      const float ds = dot16_(a0,a1,a2,a3, sys[m][0],sys[m][1],sys[m][2],sys[m][3]);
      const float d2 = fmaxf(fmaf(-2.f, ds, an2 + sb2s[m]), 0.f);
      best = fminf(best, fminf(d1, d2));
    }
  }
  atomicMin((unsigned int*)ws + OFF_BEST + nrow, __float_as_uint(best));
}

// backward: per gt-row n, min+argmin over all pred m, D1/D2 separately. grid (mt, nt, b)
__global__ __launch_bounds__(256) void k_bwd(float* __restrict__ ws) {
  __shared__ float4 ps[256][4];
  __shared__ float pb2s[256];
  const int b = blockIdx.z, nt = blockIdx.y, mt = blockIdx.x;
  const int tid = threadIdx.x;
  const int mrow = b*Nn + mt*256 + tid;
  const float4* psrc = (const float4*)(ws + OFF_PRED) + (size_t)mrow*4;
  ps[tid][0]=psrc[0]; ps[tid][1]=psrc[1]; ps[tid][2]=psrc[2]; ps[tid][3]=psrc[3];
  pb2s[tid] = ws[OFF_PN2 + mrow];
  __syncthreads();

  const int nrow = b*Nn + nt*256 + tid;
  const float4* g = (const float4*)(ws + OFF_GT)  + (size_t)nrow*4;
  const float4 g0=g[0], g1=g[1], g2=g[2], g3=g[3];
  const float4* s = (const float4*)(ws + OFF_SYM) + (size_t)nrow*4;
  const float4 s0=s[0], s1=s[1], s2=s[2], s3=s[3];
  const float gn2 = ws[OFF_GN2 + nrow], sn2 = ws[OFF_SN2 + nrow];

  unsigned long long b1 = ~0ull, b2 = ~0ull;
  const int mbase = mt * 256;
  for (int m = 0; m < 256; m++) {
    const float4 p0 = ps[m][0], p1 = ps[m][1], p2 = ps[m][2], p3 = ps[m][3];
    const float pb = pb2s[m];
    const float d1 = fmaxf(fmaf(-2.f, dot16_(g0,g1,g2,g3,p0,p1,p2,p3), gn2 + pb), 0.f);
    const float d2 = fmaxf(fmaf(-2.f, dot16_(s0,s1,s2,s3,p0,p1,p2,p3), sn2 + pb), 0.f);
    const unsigned long long c1 = ((unsigned long long)__float_as_uint(d1) << 32) | (unsigned)(mbase + m);
    const unsigned long long c2 = ((unsigned long long)__float_as_uint(d2) << 32) | (unsigned)(mbase + m);
    b1 = (c1 < b1) ? c1 : b1;
    b2 = (c2 < b2) ? c2 : b2;
  }
  atomicMin((unsigned long long*)(ws + OFF_PK1) + nrow, b1);
  atomicMin((unsigned long long*)(ws + OFF_PK2) + nrow, b2);
}

__global__ __launch_bounds__(256) void k_red(const float* __restrict__ bsp,
                                             const float* __restrict__ succ,
                                             float* __restrict__ ws) {
  __shared__ float red[4];
  const int b = blockIdx.y;
  const int n = blockIdx.x * 256 + threadIdx.x;
  const int idx = b * Nn + n;

  const float best = __uint_as_float(((const unsigned*)ws)[OFF_BEST + idx]);
  const float adds = (best < 1e30f) ? bsp[idx] * sqrtf(best) : 0.f;  // gate==0 <=> no positives <=> best==inf

  const unsigned long long p1 = ((const unsigned long long*)(ws + OFF_PK1))[idx];
  const unsigned long long p2 = ((const unsigned long long*)(ws + OFF_PK2))[idx];
  const float m1 = __uint_as_float((unsigned)(p1 >> 32));
  const float m2 = __uint_as_float((unsigned)(p2 >> 32));
  const int   i1 = (int)(p1 & 0xffffffffull);
  const int   i2 = (int)(p2 & 0xffffffffull);
  const int   id = (m2 < m1) ? i2 : i1;
  const float mg = fminf(m1, m2) * succ[idx];
  const float g2p = bsp[b*Nn + id] * mg;

  float t = blockSum_(adds, red); if (threadIdx.x == 0) atomicAdd(ws + OFF_ACC + 17, t);
  t = blockSum_(g2p, red);        if (threadIdx.x == 0) atomicAdd(ws + OFF_ACC + 18 + b, t);
}

__global__ void k_fin(const float* __restrict__ ws, float* __restrict__ out) {
  const float* acc = ws + OFF_ACC;
  float dir = 0.f, app = 0.f, off = 0.f, g2p = 0.f;
  #pragma unroll
  for (int b = 0; b < Bn; b++) {
    const float pos = fmaxf(acc[12 + b], 1.f);
    dir += acc[0 + b] / pos;
    app += acc[4 + b] / pos;
    off += acc[8 + b] / pos;
    g2p += acc[18 + b] / pos;
  }
  const float invB = 1.f / Bn;
  const float bce  = acc[16] * (1.f / (Bn * Nn));
  const float adds = acc[17] * (1.f / (Bn * Nn));
  out[0] = dir*invB + bce + off*invB + app*invB + 10.f*adds + g2p*invB;
}

extern "C" void kernel_launch(void* const* d_in, const int* in_sizes, int n_in,
                              void* d_out, int out_size, void* d_ws, size_t ws_size,
                              hipStream_t stream) {
  const float* gdir  = (const float*)d_in[0];
  const float* adirp = (const float*)d_in[1];
  const float* goff  = (const float*)d_in[2];
  const float* ppts  = (const float*)d_in[3];
  const float* bsp   = (const float*)d_in[4];
  const float* bsh   = (const float*)d_in[5];
  const float* dlab  = (const float*)d_in[6];
  const float* olab  = (const float*)d_in[7];
  const float* succ  = (const float*)d_in[8];
  const float* alab  = (const float*)d_in[9];
  const float* binv  = (const float*)d_in[10];
  const float* binw  = (const float*)d_in[11];
  const float* cpts  = (const float*)d_in[12];
  const float* scpts = (const float*)d_in[13];
  float* ws  = (float*)d_ws;
  float* out = (float*)d_out;

  k_init<<<dim3(32), dim3(256), 0, stream>>>(ws);
  k_prep<<<dim3(Nn/256, Bn), dim3(256), 0, stream>>>(gdir, adirp, goff, ppts, bsh,
                                                     dlab, olab, succ, alab,
                                                     binv, binw, cpts, scpts, ws);
  k_fwd<<<dim3(Nn/256, Nn/256, Bn), dim3(256), 0, stream>>>(succ, ws);
  k_bwd<<<dim3(Nn/256, Nn/256, Bn), dim3(256), 0, stream>>>(ws);
  k_red<<<dim3(Nn/256, Bn), dim3(256), 0, stream>>>(bsp, succ, ws);
  k_fin<<<1, 1, 0, stream>>>(ws, out);
}

// Round 3
// 136.426 us; speedup vs baseline: 1.3731x; 1.3731x over previous
//
#include <hip/hip_runtime.h>

#define Bn 4
#define Nn 2048
#define NBn 10
#define BN (Bn*Nn)
#define TM 64

// ws layout in float (4-byte) units
#define OFF_PRED 0
#define OFF_GT   (BN*16)
#define OFF_SYM  (2*BN*16)
#define OFF_PN2  (3*BN*16)
#define OFF_GN2  (OFF_PN2 + BN)
#define OFF_SN2  (OFF_GN2 + BN)
#define OFF_BEST (OFF_SN2 + BN)      // uint32 per (b,n)
#define OFF_PK1  (OFF_BEST + BN)     // u64 per (b,n) (even float offset -> 8B aligned)
#define OFF_PK2  (OFF_PK1 + 2*BN)
#define OFF_PART (OFF_PK2 + 2*BN)    // 32 blocks x 8 floats, no-init (written before read)

__device__ inline float sp_(float x) {            // jax.nn.softplus, stable form
  return fmaxf(x, 0.0f) + log1pf(expf(-fabsf(x)));
}

__device__ inline float dot16_(const float4&a0,const float4&a1,const float4&a2,const float4&a3,
                               const float4&b0,const float4&b1,const float4&b2,const float4&b3){
  float s0 = fmaf(a0.w,b0.w, fmaf(a0.z,b0.z, fmaf(a0.y,b0.y, a0.x*b0.x)));
  float s1 = fmaf(a1.w,b1.w, fmaf(a1.z,b1.z, fmaf(a1.y,b1.y, a1.x*b1.x)));
  float s2 = fmaf(a2.w,b2.w, fmaf(a2.z,b2.z, fmaf(a2.y,b2.y, a2.x*b2.x)));
  float s3 = fmaf(a3.w,b3.w, fmaf(a3.z,b3.z, fmaf(a3.y,b3.y, a3.x*b3.x)));
  return (s0+s1)+(s2+s3);
}

__device__ inline float blockSum_(float v, float* red) {
  #pragma unroll
  for (int o = 32; o > 0; o >>= 1) v += __shfl_down(v, o, 64);
  __syncthreads();
  if ((threadIdx.x & 63) == 0) red[threadIdx.x >> 6] = v;
  __syncthreads();
  return red[0] + red[1] + red[2] + red[3];
}

// ---------- prep: frames, control points, norms, min-state init. grid (BN/64), block 64.
__global__ __launch_bounds__(64) void k_prep(
    const float* __restrict__ gdir, const float* __restrict__ adirp,
    const float* __restrict__ goff, const float* __restrict__ ppts,
    const float* __restrict__ dlab, const float* __restrict__ olab,
    const float* __restrict__ alab,
    const float* __restrict__ binv,
    const float* __restrict__ cpts, const float* __restrict__ scpts,
    float* __restrict__ ws)
{
  const int idx = blockIdx.x * 64 + threadIdx.x;

  const float gd0=gdir[idx*3+0],  gd1=gdir[idx*3+1],  gd2=gdir[idx*3+2];
  const float ad0=adirp[idx*3+0], ad1=adirp[idx*3+1], ad2=adirp[idx*3+2];
  const float dl0=dlab[idx*3+0],  dl1=dlab[idx*3+1],  dl2=dlab[idx*3+2];
  const float al0=alab[idx*3+0],  al1=alab[idx*3+1],  al2=alab[idx*3+2];
  const float pt0=ppts[idx*3+0],  pt1=ppts[idx*3+1],  pt2=ppts[idx*3+2];

  // argmax (first occurrence, matches jnp.argmax)
  float bv = goff[idx*NBn]; int ap = 0;
  #pragma unroll
  for (int k = 1; k < NBn; k++) { float v = goff[idx*NBn+k]; if (v > bv) { bv = v; ap = k; } }
  float bg = olab[idx*NBn]; int ag = 0;
  #pragma unroll
  for (int k = 1; k < NBn; k++) { float v = olab[idx*NBn+k]; if (v > bg) { bg = v; ag = k; } }
  const float tp = binv[ap] * 0.5f;
  const float tg = binv[ag] * 0.5f;

  // frames: cross = cross(approach, base); t = pt + 0.5*thickness*base
  const float cp0 = ad1*gd2 - ad2*gd1, cp1 = ad2*gd0 - ad0*gd2, cp2 = ad0*gd1 - ad1*gd0;
  const float cg0 = al1*dl2 - al2*dl1, cg1 = al2*dl0 - al0*dl2, cg2 = al0*dl1 - al1*dl0;
  const float tpx = pt0 + tp*gd0, tpy = pt1 + tp*gd1, tpz = pt2 + tp*gd2;
  const float tgx = pt0 + tg*dl0, tgy = pt1 + tg*dl1, tgz = pt2 + tg*dl2;

  float pcp[15], gcp[15], hcp[15];
  float pn2 = 0.f, gn2 = 0.f, sn2 = 0.f;
  #pragma unroll
  for (int p = 0; p < 5; p++) {
    const float cx = cpts[p*3], cy = cpts[p*3+1], cz = cpts[p*3+2];
    const float sx = scpts[p*3], sy = scpts[p*3+1], sz = scpts[p*3+2];
    float x, y, z;
    x = gd0*cx + cp0*cy + ad0*cz + tpx;
    y = gd1*cx + cp1*cy + ad1*cz + tpy;
    z = gd2*cx + cp2*cy + ad2*cz + tpz;
    pcp[p*3+0]=x; pcp[p*3+1]=y; pcp[p*3+2]=z;
    pn2 = fmaf(x,x, fmaf(y,y, fmaf(z,z, pn2)));
    x = dl0*cx + cg0*cy + al0*cz + tgx;
    y = dl1*cx + cg1*cy + al1*cz + tgy;
    z = dl2*cx + cg2*cy + al2*cz + tgz;
    gcp[p*3+0]=x; gcp[p*3+1]=y; gcp[p*3+2]=z;
    gn2 = fmaf(x,x, fmaf(y,y, fmaf(z,z, gn2)));
    x = dl0*sx + cg0*sy + al0*sz + tgx;
    y = dl1*sx + cg1*sy + al1*sz + tgy;
    z = dl2*sx + cg2*sy + al2*sz + tgz;
    hcp[p*3+0]=x; hcp[p*3+1]=y; hcp[p*3+2]=z;
    sn2 = fmaf(x,x, fmaf(y,y, fmaf(z,z, sn2)));
  }

  float4* pd = (float4*)(ws + OFF_PRED) + (size_t)idx*4;
  pd[0]=make_float4(pcp[0],pcp[1],pcp[2],pcp[3]);
  pd[1]=make_float4(pcp[4],pcp[5],pcp[6],pcp[7]);
  pd[2]=make_float4(pcp[8],pcp[9],pcp[10],pcp[11]);
  pd[3]=make_float4(pcp[12],pcp[13],pcp[14],0.f);
  float4* gdst = (float4*)(ws + OFF_GT) + (size_t)idx*4;
  gdst[0]=make_float4(gcp[0],gcp[1],gcp[2],gcp[3]);
  gdst[1]=make_float4(gcp[4],gcp[5],gcp[6],gcp[7]);
  gdst[2]=make_float4(gcp[8],gcp[9],gcp[10],gcp[11]);
  gdst[3]=make_float4(gcp[12],gcp[13],gcp[14],0.f);
  float4* sdst = (float4*)(ws + OFF_SYM) + (size_t)idx*4;
  sdst[0]=make_float4(hcp[0],hcp[1],hcp[2],hcp[3]);
  sdst[1]=make_float4(hcp[4],hcp[5],hcp[6],hcp[7]);
  sdst[2]=make_float4(hcp[8],hcp[9],hcp[10],hcp[11]);
  sdst[3]=make_float4(hcp[12],hcp[13],hcp[14],0.f);
  ws[OFF_PN2+idx] = pn2; ws[OFF_GN2+idx] = gn2; ws[OFF_SN2+idx] = sn2;

  // per-idx min-state init (k_pair runs strictly after)
  ((unsigned*)ws)[OFF_BEST + idx] = 0x7F800000u;   // +inf
  ((unsigned long long*)(ws + OFF_PK1))[idx] = ~0ull;
  ((unsigned long long*)(ws + OFF_PK2))[idx] = ~0ull;
}

// ---------- fused pairwise kernel. grid (Nn/TM, Nn/256, Bn), block 256.
// phase A: forward row-min over succ-positive gt columns (min of D1,D2)
// phase B: backward min+argmin over pred columns, D1/D2 separately (packed u64)
__global__ __launch_bounds__(256) void k_pair(const float* __restrict__ succ,
                                              float* __restrict__ ws) {
  __shared__ float4 gts[TM][4], sys[TM][4], prs[TM][4];
  __shared__ float gb2[TM], sb2[TM], pb2[TM], msk[TM];
  const int mt = blockIdx.x, nt = blockIdx.y, b = blockIdx.z;
  const int tid = threadIdx.x;
  const int r = tid >> 2, p = tid & 3;           // 256 threads stage 64 rows x 4 float4
  const int mrow = b*Nn + mt*TM + r;
  gts[r][p] = ((const float4*)(ws + OFF_GT))  [(size_t)mrow*4 + p];
  sys[r][p] = ((const float4*)(ws + OFF_SYM)) [(size_t)mrow*4 + p];
  prs[r][p] = ((const float4*)(ws + OFF_PRED))[(size_t)mrow*4 + p];
  if      (p == 0) gb2[r] = ws[OFF_GN2 + mrow];
  else if (p == 1) sb2[r] = ws[OFF_SN2 + mrow];
  else if (p == 2) pb2[r] = ws[OFF_PN2 + mrow];
  else             msk[r] = succ[mrow];
  __syncthreads();

  const int nrow = b*Nn + nt*256 + tid;
  const float INF = __int_as_float(0x7F800000);

  // ---- phase A: own pred row vs gt/sym tile ----
  {
    const float4* pa = (const float4*)(ws + OFF_PRED) + (size_t)nrow*4;
    const float4 a0 = pa[0], a1 = pa[1], a2 = pa[2], a3 = pa[3];
    const float an2 = ws[OFF_PN2 + nrow];
    float best = INF;
    for (int m = 0; m < TM; m++) {
      if (msk[m] != 0.0f) {
        const float d1 = fmaxf(fmaf(-2.f, dot16_(a0,a1,a2,a3, gts[m][0],gts[m][1],gts[m][2],gts[m][3]), an2 + gb2[m]), 0.f);
        const float d2 = fmaxf(fmaf(-2.f, dot16_(a0,a1,a2,a3, sys[m][0],sys[m][1],sys[m][2],sys[m][3]), an2 + sb2[m]), 0.f);
        best = fminf(best, fminf(d1, d2));
      }
    }
    if (best < INF)
      atomicMin((unsigned int*)ws + OFF_BEST + nrow, __float_as_uint(best));
  }

  // ---- phase B: own gt/sym row vs pred tile ----
  {
    const float4* g = (const float4*)(ws + OFF_GT)  + (size_t)nrow*4;
    const float4 g0=g[0], g1=g[1], g2=g[2], g3=g[3];
    const float4* s = (const float4*)(ws + OFF_SYM) + (size_t)nrow*4;
    const float4 s0=s[0], s1=s[1], s2=s[2], s3=s[3];
    const float gn2 = ws[OFF_GN2 + nrow], sn2 = ws[OFF_SN2 + nrow];
    unsigned long long b1 = ~0ull, b2 = ~0ull;
    for (int m = 0; m < TM; m++) {
      const float4 p0 = prs[m][0], p1 = prs[m][1], p2 = prs[m][2], p3 = prs[m][3];
      const float pb = pb2[m];
      const float d1 = fmaxf(fmaf(-2.f, dot16_(g0,g1,g2,g3,p0,p1,p2,p3), gn2 + pb), 0.f);
      const float d2 = fmaxf(fmaf(-2.f, dot16_(s0,s1,s2,s3,p0,p1,p2,p3), sn2 + pb), 0.f);
      const unsigned long long c1 = ((unsigned long long)__float_as_uint(d1) << 32) | (unsigned)(mt*TM + m);
      const unsigned long long c2 = ((unsigned long long)__float_as_uint(d2) << 32) | (unsigned)(mt*TM + m);
      b1 = (c1 < b1) ? c1 : b1;
      b2 = (c2 < b2) ? c2 : b2;
    }
    atomicMin((unsigned long long*)(ws + OFF_PK1) + nrow, b1);
    atomicMin((unsigned long long*)(ws + OFF_PK2) + nrow, b2);
  }
}

// ---------- reduce: per-point losses + adds/g2p, per-block partials (no atomics).
// grid (Nn/256, Bn), block 256. partial[(b*8+nt)*8 + c], c: 0=dir 1=app 2=off 3=succ 4=bce 5=adds 6=g2p
__global__ __launch_bounds__(256) void k_red(
    const float* __restrict__ bsp,  const float* __restrict__ bsh,
    const float* __restrict__ succ,
    const float* __restrict__ gdir, const float* __restrict__ adirp,
    const float* __restrict__ dlab, const float* __restrict__ alab,
    const float* __restrict__ goff, const float* __restrict__ olab,
    const float* __restrict__ binw,
    float* __restrict__ ws)
{
  __shared__ float red[4];
  const int b = blockIdx.y, nt = blockIdx.x;
  const int idx = b*Nn + nt*256 + threadIdx.x;
  const float sc = succ[idx];

  // forward ADD-S term
  const float best = __uint_as_float(((const unsigned*)ws)[OFF_BEST + idx]);
  const float adds = (best < 1e30f) ? bsp[idx] * sqrtf(best) : 0.f;  // inf <=> zero positives <=> gate 0

  // backward term
  const unsigned long long p1 = ((const unsigned long long*)(ws + OFF_PK1))[idx];
  const unsigned long long p2 = ((const unsigned long long*)(ws + OFF_PK2))[idx];
  const float m1 = __uint_as_float((unsigned)(p1 >> 32));
  const float m2 = __uint_as_float((unsigned)(p2 >> 32));
  const int   i1 = (int)(p1 & 0xffffffffull);
  const int   i2 = (int)(p2 & 0xffffffffull);
  const int   id = (m2 < m1) ? i2 : i1;
  const float g2p = bsp[b*Nn + id] * fminf(m1, m2) * sc;

  // cheap per-point losses (recomputed here; saves a ws round-trip)
  const float gd0=gdir[idx*3+0],  gd1=gdir[idx*3+1],  gd2=gdir[idx*3+2];
  const float ad0=adirp[idx*3+0], ad1=adirp[idx*3+1], ad2=adirp[idx*3+2];
  const float dl0=dlab[idx*3+0],  dl1=dlab[idx*3+1],  dl2=dlab[idx*3+2];
  const float al0=alab[idx*3+0],  al1=alab[idx*3+1],  al2=alab[idx*3+2];

  const float cosd = 1.f - (dl0*gd0 + dl1*gd1 + dl2*gd2);
  const float proj = gd0*al0 + gd1*al1 + gd2*al2;
  const float o0 = al0 - proj*gd0, o1 = al1 - proj*gd1, o2 = al2 - proj*gd2;
  const float on = sqrtf(o0*o0 + o1*o1 + o2*o2);
  const float inv = 1.f / fmaxf(on, 1e-12f);
  const float cosa = 1.f - inv*(o0*ad0 + o1*ad1 + o2*ad2);

  float offv = 0.f;
  #pragma unroll
  for (int k = 0; k < NBn; k++) {
    const float x = goff[idx*NBn+k], lab = olab[idx*NBn+k];
    const float bce = lab * sp_(-x) + (1.f - lab) * sp_(x);
    offv = fmaf(binw[k], bce, offv);
  }
  offv *= (1.0f / NBn);
  const float sb = bsh[idx];
  const float sbce = sc * sp_(-sb) + (1.f - sc) * sp_(sb);

  float* part = ws + OFF_PART + (size_t)(b*8 + nt)*8;
  float t;
  t = blockSum_(cosd*sc, red); if (threadIdx.x == 0) part[0] = t;
  t = blockSum_(cosa*sc, red); if (threadIdx.x == 0) part[1] = t;
  t = blockSum_(offv*sc, red); if (threadIdx.x == 0) part[2] = t;
  t = blockSum_(sc, red);      if (threadIdx.x == 0) part[3] = t;
  t = blockSum_(sbce, red);    if (threadIdx.x == 0) part[4] = t;
  t = blockSum_(adds, red);    if (threadIdx.x == 0) part[5] = t;
  t = blockSum_(g2p, red);     if (threadIdx.x == 0) part[6] = t;
}

// ---------- finalize: 1 block, 64 threads, wave-only reduction of 32x7 partials
__global__ __launch_bounds__(64) void k_fin(const float* __restrict__ ws, float* __restrict__ out) {
  const int t = threadIdx.x;
  float v[7];
  #pragma unroll
  for (int c = 0; c < 7; c++) v[c] = (t < 32) ? ws[OFF_PART + t*8 + c] : 0.f;
  #pragma unroll
  for (int o = 1; o < 8; o <<= 1) {
    #pragma unroll
    for (int c = 0; c < 7; c++) v[c] += __shfl_xor(v[c], o, 64);
  }
  // each 8-lane group (t<32) now holds per-b sums (b = t>>3)
  const float pos = fmaxf(v[3], 1.f);
  float vb   = (v[0] + v[1] + v[2] + v[6]) / pos;   // dir + app + off + g2p, per-b normalized
  float bce  = v[4];
  float adds = v[5];
  #pragma unroll
  for (int o = 8; o < 32; o <<= 1) {
    vb   += __shfl_xor(vb,   o, 64);
    bce  += __shfl_xor(bce,  o, 64);
    adds += __shfl_xor(adds, o, 64);
  }
  if (t == 0)
    out[0] = vb * 0.25f + bce * (1.f/BN) + 10.f * adds * (1.f/BN);
}

extern "C" void kernel_launch(void* const* d_in, const int* in_sizes, int n_in,
                              void* d_out, int out_size, void* d_ws, size_t ws_size,
                              hipStream_t stream) {
  const float* gdir  = (const float*)d_in[0];
  const float* adirp = (const float*)d_in[1];
  const float* goff  = (const float*)d_in[2];
  const float* ppts  = (const float*)d_in[3];
  const float* bsp   = (const float*)d_in[4];
  const float* bsh   = (const float*)d_in[5];
  const float* dlab  = (const float*)d_in[6];
  const float* olab  = (const float*)d_in[7];
  const float* succ  = (const float*)d_in[8];
  const float* alab  = (const float*)d_in[9];
  const float* binv  = (const float*)d_in[10];
  const float* binw  = (const float*)d_in[11];
  const float* cpts  = (const float*)d_in[12];
  const float* scpts = (const float*)d_in[13];
  float* ws  = (float*)d_ws;
  float* out = (float*)d_out;

  k_prep<<<dim3(BN/64), dim3(64), 0, stream>>>(gdir, adirp, goff, ppts,
                                               dlab, olab, alab, binv, cpts, scpts, ws);
  k_pair<<<dim3(Nn/TM, Nn/256, Bn), dim3(256), 0, stream>>>(succ, ws);
  k_red<<<dim3(Nn/256, Bn), dim3(256), 0, stream>>>(bsp, bsh, succ, gdir, adirp,
                                                    dlab, alab, goff, olab, binw, ws);
  k_fin<<<1, 64, 0, stream>>>(ws, out);
}